// Round 1
// baseline (227.554 us; speedup 1.0000x reference)
//
#include <hip/hip_runtime.h>
#include <math.h>

#define NROWS 4096
#define VCOLS 32000

// Constants from reference: LS=0.1, CONF=0.9, SM=0.1/31999
__device__ __constant__ float d_dummy; // (none needed)

constexpr float CONF_F   = 0.9f;
constexpr float SM_F     = 0.1f / 31999.0f;          // 3.1250977e-06
constexpr float KL_CONST = -1.36242896f;             // 0.9*ln(0.9) + 0.1*ln(SM)
constexpr float COEF_T   = CONF_F - SM_F;            // weight on logp[target]

// ---------------- kernel 1: init first-occurrence table ----------------
__global__ void k_init(int* __restrict__ ftable) {
    int v = blockIdx.x * blockDim.x + threadIdx.x;
    if (v < VCOLS) ftable[v] = NROWS;   // sentinel: never seen
}

// ---------------- kernel 2: first occurrence via atomicMin + cleaned targets
__global__ void k_scatter(const int* __restrict__ target,
                          int* __restrict__ ftable,
                          int* __restrict__ tclean) {
    int j = blockIdx.x * blockDim.x + threadIdx.x;
    if (j < NROWS) {
        int t  = target[j];
        int tc = (t != -1) ? t : 0;     // tgt = where(valid, target, PAD)
        tclean[j] = tc;
        atomicMin(&ftable[tc], j);
    }
}

// ---------------- kernel 3: per-row softmax stats + KL + unlikelihood ----
__global__ __launch_bounds__(256)
void k_main(const float* __restrict__ X,
            const int*   __restrict__ target,
            const int*   __restrict__ tclean,
            const int*   __restrict__ ftable,
            float* __restrict__ kl_rows,
            float* __restrict__ custom_rows) {
    const int i   = blockIdx.x;
    const int tid = threadIdx.x;

    __shared__ float sval[NROWS];       // gathered candidate logits (16 KB)
    __shared__ float rm[256], rz[256], rs[256];
    __shared__ float s_logZ;

    const bool valid = (target[i] != -1);
    if (!valid) {
        if (tid == 0) { kl_rows[i] = 0.0f; custom_rows[i] = 0.0f; }
        return;
    }

    const int    mytgt = tclean[i];
    const float* row   = X + (size_t)i * VCOLS;

    // ---- phase 1: gather candidate logits (first occurrences j < i) ----
    // Issued before the streaming pass so these lines are L2-warm for it.
    for (int j = tid; j < i; j += 256) {
        int   v  = tclean[j];
        float xv = -INFINITY;           // sentinel -> contributes 0 later
        if (v != 0 && v != mytgt && ftable[v] == j) xv = row[v];
        sval[j] = xv;
    }

    // ---- phase 2: single-pass online softmax + sum of logits ----
    float m = -INFINITY, Z = 0.0f, sx = 0.0f;
    const float4* row4 = (const float4*)row;     // row stride 128000 B, 16B aligned
    for (int e = tid; e < VCOLS / 4; e += 256) {
        float4 v  = row4[e];
        float  m4 = fmaxf(fmaxf(v.x, v.y), fmaxf(v.z, v.w));
        if (m4 > m) { Z *= __expf(m - m4); m = m4; }   // rare branch (~5/thread)
        Z += __expf(v.x - m) + __expf(v.y - m) + __expf(v.z - m) + __expf(v.w - m);
        sx += (v.x + v.y) + (v.z + v.w);
    }
    rm[tid] = m; rz[tid] = Z; rs[tid] = sx;
    __syncthreads();
    for (int s = 128; s > 0; s >>= 1) {
        if (tid < s) {
            float m2 = rm[tid + s], z2 = rz[tid + s];
            float mm = fmaxf(rm[tid], m2);
            rz[tid]  = rz[tid] * __expf(rm[tid] - mm) + z2 * __expf(m2 - mm);
            rm[tid]  = mm;
            rs[tid] += rs[tid + s];
        }
        __syncthreads();
    }
    if (tid == 0) {
        float logZ   = rm[0] + __logf(rz[0]);
        s_logZ       = logZ;
        float x_t    = row[mytgt];
        float logp_t = x_t - logZ;
        float sumlogp = rs[0] - (float)VCOLS * logZ;   // sum_j logp[i,j]
        kl_rows[i] = KL_CONST - COEF_T * logp_t - SM_F * sumlogp;
    }
    __syncthreads();
    const float logZ = s_logZ;

    // ---- phase 4: unlikelihood term over gathered candidates ----
    float acc = 0.0f;
    for (int j = tid; j < i; j += 256) {
        float xv = sval[j];                     // -inf -> p=0 -> term 0
        float p  = __expf(xv - logZ);
        float om = fmaxf(1.0f - p, 1e-5f);
        acc -= __logf(om);
    }
    rs[tid] = acc;
    __syncthreads();
    for (int s = 128; s > 0; s >>= 1) {
        if (tid < s) rs[tid] += rs[tid + s];
        __syncthreads();
    }
    if (tid == 0) custom_rows[i] = rs[0];
}

// ---------------- kernel 4: deterministic final reduction ----------------
__global__ void k_final(const float* __restrict__ kl_rows,
                        const float* __restrict__ custom_rows,
                        const int*   __restrict__ target,
                        float* __restrict__ out) {
    __shared__ float sl[256], sc[256], sn[256];
    int tid = threadIdx.x;
    float L = 0.0f, C = 0.0f, Nn = 0.0f;
    for (int j = tid; j < NROWS; j += 256) {
        L += kl_rows[j];
        C += custom_rows[j];
        int t = target[j];
        if (t != -1 && t != 0) Nn += 1.0f;    // valid & (tgt != PAD)
    }
    sl[tid] = L; sc[tid] = C; sn[tid] = Nn;
    __syncthreads();
    for (int s = 128; s > 0; s >>= 1) {
        if (tid < s) { sl[tid] += sl[tid+s]; sc[tid] += sc[tid+s]; sn[tid] += sn[tid+s]; }
        __syncthreads();
    }
    if (tid == 0) {
        float norm = sn[0];
        out[0] = sl[0] / norm + 0.1f * sc[0] / norm;
    }
}

extern "C" void kernel_launch(void* const* d_in, const int* in_sizes, int n_in,
                              void* d_out, int out_size, void* d_ws, size_t ws_size,
                              hipStream_t stream) {
    const float* X      = (const float*)d_in[0];   // (N, V) float32
    const int*   target = (const int*)d_in[1];     // (N,)   int32
    float*       out    = (float*)d_out;

    char* ws = (char*)d_ws;
    int*   ftable      = (int*)  (ws);                               // V ints   = 128000 B
    int*   tclean      = (int*)  (ws + 128000);                      // N ints   =  16384 B
    float* kl_rows     = (float*)(ws + 128000 + 16384);              // N floats =  16384 B
    float* custom_rows = (float*)(ws + 128000 + 2 * 16384);          // N floats =  16384 B

    k_init   <<<(VCOLS + 255) / 256, 256, 0, stream>>>(ftable);
    k_scatter<<<(NROWS + 255) / 256, 256, 0, stream>>>(target, ftable, tclean);
    k_main   <<<NROWS,               256, 0, stream>>>(X, target, tclean, ftable,
                                                       kl_rows, custom_rows);
    k_final  <<<1,                   256, 0, stream>>>(kl_rows, custom_rows, target, out);
}

// Round 2
// 118.772 us; speedup vs baseline: 1.9159x; 1.9159x over previous
//
#include <hip/hip_runtime.h>
#include <math.h>

#define NROWS 4096
#define VCOLS 32000

// Constants from reference: LS=0.1, CONF=0.9, SM=0.1/31999
constexpr float CONF_F   = 0.9f;
constexpr float SM_F     = 0.1f / 31999.0f;          // 3.1250977e-06
constexpr float KL_CONST = -1.36242896f;             // 0.9*ln(0.9) + 0.1*ln(SM)
constexpr float COEF_T   = CONF_F - SM_F;            // weight on logp[target]

// ---------------- kernel 1: init first-occurrence table ----------------
__global__ void k_init(int* __restrict__ ftable) {
    int v = blockIdx.x * blockDim.x + threadIdx.x;
    if (v < VCOLS) ftable[v] = NROWS;   // sentinel: never a candidate
}

// ---------------- kernel 2: first occurrence via atomicMin + cleaned targets
__global__ void k_scatter(const int* __restrict__ target,
                          int* __restrict__ ftable,
                          int* __restrict__ tclean) {
    int j = blockIdx.x * blockDim.x + threadIdx.x;
    if (j < NROWS) {
        int t  = target[j];
        int tc = (t != -1) ? t : 0;     // tgt = where(valid, target, PAD)
        tclean[j] = tc;
        // column 0 (PAD) is excluded from neg targets in the reference
        // (neg[:,0]=0), so never mark it -> ftable[0] stays NROWS.
        if (tc != 0) atomicMin(&ftable[tc], j);
    }
}

// ---------------- kernel 3: fused single-pass row kernel -----------------
// One block per row. Single coalesced sweep over the row computes:
//   - online softmax stats (m, Z) and sum of logits
//   - gold-token logit (v == tgt_i)
//   - candidate logits written to deterministic LDS slot cand[ftable[v]]
//     (candidate iff ftable[v] < i and v != tgt_i; ftable[0]==NROWS)
// Then logZ reduction, KL term, and the unlikelihood tail over the LDS list.
__global__ __launch_bounds__(256)
void k_main(const float* __restrict__ X,
            const int*   __restrict__ target,
            const int*   __restrict__ tclean,
            const int*   __restrict__ ftable,
            float* __restrict__ kl_rows,
            float* __restrict__ custom_rows) {
    const int i   = blockIdx.x;
    const int tid = threadIdx.x;

    __shared__ float cand[NROWS];       // candidate logits by first-occ pos (16 KB)
    __shared__ float rm[256], rz[256], rs[256];
    __shared__ float s_logZ, s_xt;

    const bool valid = (target[i] != -1);
    if (!valid) {
        if (tid == 0) { kl_rows[i] = 0.0f; custom_rows[i] = 0.0f; }
        return;
    }

    const int    mytgt = tclean[i];
    const float* row   = X + (size_t)i * VCOLS;

    // init candidate slots we will read later ([0, i))
    for (int j = tid; j < i; j += 256) cand[j] = -INFINITY;
    __syncthreads();

    // ---- single coalesced sweep ----
    float m = -INFINITY, Z = 0.0f, sx = 0.0f;
    const float4* row4 = (const float4*)row;        // 16B-aligned (stride 128000B)
    const int4*   ft4  = (const int4*)ftable;
    for (int e = tid; e < VCOLS / 4; e += 256) {
        float4 x = row4[e];
        int4   f = ft4[e];
        float  m4 = fmaxf(fmaxf(x.x, x.y), fmaxf(x.z, x.w));
        if (m4 > m) { Z *= __expf(m - m4); m = m4; }      // rare (~5/thread)
        Z += __expf(x.x - m) + __expf(x.y - m) + __expf(x.z - m) + __expf(x.w - m);
        sx += (x.x + x.y) + (x.z + x.w);

        int base = e * 4;
        if (f.x < i && base     != mytgt) cand[f.x] = x.x;
        if (f.y < i && base + 1 != mytgt) cand[f.y] = x.y;
        if (f.z < i && base + 2 != mytgt) cand[f.z] = x.z;
        if (f.w < i && base + 3 != mytgt) cand[f.w] = x.w;
        unsigned d = (unsigned)(mytgt - base);
        if (d < 4u) s_xt = (d == 0u) ? x.x : (d == 1u) ? x.y : (d == 2u) ? x.z : x.w;
    }
    rm[tid] = m; rz[tid] = Z; rs[tid] = sx;
    __syncthreads();
    for (int s = 128; s > 0; s >>= 1) {
        if (tid < s) {
            float m2 = rm[tid + s], z2 = rz[tid + s];
            float mm = fmaxf(rm[tid], m2);
            rz[tid]  = rz[tid] * __expf(rm[tid] - mm) + z2 * __expf(m2 - mm);
            rm[tid]  = mm;
            rs[tid] += rs[tid + s];
        }
        __syncthreads();
    }
    if (tid == 0) {
        float logZ   = rm[0] + __logf(rz[0]);
        s_logZ       = logZ;
        float logp_t = s_xt - logZ;
        float sumlogp = rs[0] - (float)VCOLS * logZ;      // sum_j logp[i,j]
        kl_rows[i] = KL_CONST - COEF_T * logp_t - SM_F * sumlogp;
    }
    __syncthreads();
    const float logZ = s_logZ;

    // ---- unlikelihood tail over the candidate list ----
    float acc = 0.0f;
    for (int j = tid; j < i; j += 256) {
        float xv = cand[j];                 // -inf -> p=0 -> term 0
        float p  = __expf(xv - logZ);
        float om = fmaxf(1.0f - p, 1e-5f);
        acc -= __logf(om);
    }
    rs[tid] = acc;
    __syncthreads();
    for (int s = 128; s > 0; s >>= 1) {
        if (tid < s) rs[tid] += rs[tid + s];
        __syncthreads();
    }
    if (tid == 0) custom_rows[i] = rs[0];
}

// ---------------- kernel 4: deterministic final reduction ----------------
__global__ void k_final(const float* __restrict__ kl_rows,
                        const float* __restrict__ custom_rows,
                        const int*   __restrict__ target,
                        float* __restrict__ out) {
    __shared__ float sl[256], sc[256], sn[256];
    int tid = threadIdx.x;
    float L = 0.0f, C = 0.0f, Nn = 0.0f;
    for (int j = tid; j < NROWS; j += 256) {
        L += kl_rows[j];
        C += custom_rows[j];
        int t = target[j];
        if (t != -1 && t != 0) Nn += 1.0f;    // valid & (tgt != PAD)
    }
    sl[tid] = L; sc[tid] = C; sn[tid] = Nn;
    __syncthreads();
    for (int s = 128; s > 0; s >>= 1) {
        if (tid < s) { sl[tid] += sl[tid+s]; sc[tid] += sc[tid+s]; sn[tid] += sn[tid+s]; }
        __syncthreads();
    }
    if (tid == 0) {
        float norm = sn[0];
        out[0] = sl[0] / norm + 0.1f * sc[0] / norm;
    }
}

extern "C" void kernel_launch(void* const* d_in, const int* in_sizes, int n_in,
                              void* d_out, int out_size, void* d_ws, size_t ws_size,
                              hipStream_t stream) {
    const float* X      = (const float*)d_in[0];   // (N, V) float32
    const int*   target = (const int*)d_in[1];     // (N,)   int32
    float*       out    = (float*)d_out;

    char* ws = (char*)d_ws;
    int*   ftable      = (int*)  (ws);                               // V ints   = 128000 B
    int*   tclean      = (int*)  (ws + 128000);                      // N ints   =  16384 B
    float* kl_rows     = (float*)(ws + 128000 + 16384);              // N floats =  16384 B
    float* custom_rows = (float*)(ws + 128000 + 2 * 16384);          // N floats =  16384 B

    k_init   <<<(VCOLS + 255) / 256, 256, 0, stream>>>(ftable);
    k_scatter<<<(NROWS + 255) / 256, 256, 0, stream>>>(target, ftable, tclean);
    k_main   <<<NROWS,               256, 0, stream>>>(X, target, tclean, ftable,
                                                       kl_rows, custom_rows);
    k_final  <<<1,                   256, 0, stream>>>(kl_rows, custom_rows, target, out);
}

// Round 4
// 116.408 us; speedup vs baseline: 1.9548x; 1.0203x over previous
//
#include <hip/hip_runtime.h>
#include <math.h>

#define NROWS 4096
#define VCOLS 32000
#define NV4   (VCOLS / 4)     // 8000 float4 per row

// Constants from reference: LS=0.1, CONF=0.9, SM=0.1/31999
constexpr float CONF_F   = 0.9f;
constexpr float SM_F     = 0.1f / 31999.0f;          // 3.1250977e-06
constexpr float KL_CONST = -1.36242896f;             // 0.9*ln(0.9) + 0.1*ln(SM)
constexpr float COEF_T   = CONF_F - SM_F;            // weight on logp[target]

// ---------------- kernel 1: init first-occurrence table (u32) -----------
__global__ void k_init(int* __restrict__ ft32) {
    int v = blockIdx.x * blockDim.x + threadIdx.x;
    if (v < VCOLS) ft32[v] = NROWS;     // sentinel: never a candidate
}

// ---------------- kernel 2: first occurrence via atomicMin --------------
__global__ void k_scatter(const int* __restrict__ target,
                          int* __restrict__ ft32,
                          int* __restrict__ tclean) {
    int j = blockIdx.x * blockDim.x + threadIdx.x;
    if (j < NROWS) {
        int t  = target[j];
        int tc = (t != -1) ? t : 0;     // tgt = where(valid, target, PAD)
        tclean[j] = tc;
        // column 0 (PAD) excluded from neg targets (neg[:,0]=0): never mark.
        if (tc != 0) atomicMin(&ft32[tc], j);
    }
}

// ---------------- kernel 3: pack table to u16 (values <= 4096) ----------
__global__ void k_pack(const int* __restrict__ ft32,
                       unsigned short* __restrict__ ft16) {
    int v = blockIdx.x * blockDim.x + threadIdx.x;
    if (v < VCOLS) ft16[v] = (unsigned short)ft32[v];
}

// ---------------- kernel 4: fused single-pass row kernel ----------------
// One block per row, one coalesced sweep: online softmax stats + sum of
// logits + gold logit + candidate logits into deterministic LDS slots
// cand[ft16[v]] (candidate iff ft16[v] < i, v != tgt_i; ft16[0]==NROWS).
// Unrolled x4 with up-front loads for deep MLP; chunk-max shortens the
// loop-carried (m, Z) chain to one update per 16 floats.
__global__ __launch_bounds__(256)
void k_main(const float* __restrict__ X,
            const int*   __restrict__ target,
            const int*   __restrict__ tclean,
            const unsigned short* __restrict__ ft16,
            float* __restrict__ kl_rows,
            float* __restrict__ custom_rows) {
    const int i   = blockIdx.x;
    const int tid = threadIdx.x;

    __shared__ float cand[NROWS];       // candidate logits by first-occ pos (16 KB)
    __shared__ float rm[256], rz[256], rs[256];
    __shared__ float s_logZ, s_xt;

    const bool valid = (target[i] != -1);
    if (!valid) {
        if (tid == 0) { kl_rows[i] = 0.0f; custom_rows[i] = 0.0f; }
        return;
    }

    const int    mytgt = tclean[i];
    const float* row   = X + (size_t)i * VCOLS;

    for (int j = tid; j < i; j += 256) cand[j] = -INFINITY;
    __syncthreads();

    const float4* row4 = (const float4*)row;    // 16B aligned (stride 128000B)
    const int2*   ft2  = (const int2*)ft16;     // 4 u16 per float4

    float m = -INFINITY, Z = 0.0f, sx = 0.0f;

#define MAX4(xx) fmaxf(fmaxf((xx).x, (xx).y), fmaxf((xx).z, (xx).w))
#define PROC(xx, ff, ee) do {                                                \
        Z  += __expf((xx).x - m) + __expf((xx).y - m)                        \
            + __expf((xx).z - m) + __expf((xx).w - m);                       \
        sx += ((xx).x + (xx).y) + ((xx).z + (xx).w);                         \
        int base_ = (ee) * 4;                                                \
        int a0_ = (ff).x & 0xFFFF, a1_ = (int)(((unsigned)(ff).x) >> 16);    \
        int a2_ = (ff).y & 0xFFFF, a3_ = (int)(((unsigned)(ff).y) >> 16);    \
        unsigned d_ = (unsigned)(mytgt - base_);                             \
        if (a0_ < i && d_ != 0u) cand[a0_] = (xx).x;                         \
        if (a1_ < i && d_ != 1u) cand[a1_] = (xx).y;                         \
        if (a2_ < i && d_ != 2u) cand[a2_] = (xx).z;                         \
        if (a3_ < i && d_ != 3u) cand[a3_] = (xx).w;                         \
        if (d_ < 4u) s_xt = (d_ == 0u) ? (xx).x : (d_ == 1u) ? (xx).y        \
                          : (d_ == 2u) ? (xx).z : (xx).w;                    \
    } while (0)

    for (int eb = tid; eb < NV4; eb += 1024) {
        const bool v1 = (eb +  256) < NV4;
        const bool v2 = (eb +  512) < NV4;
        const bool v3 = (eb +  768) < NV4;
        float4 x0, x1, x2, x3;
        int2   f0, f1, f2, f3;
        x0 = row4[eb];              f0 = ft2[eb];
        if (v1) { x1 = row4[eb + 256]; f1 = ft2[eb + 256]; }
        if (v2) { x2 = row4[eb + 512]; f2 = ft2[eb + 512]; }
        if (v3) { x3 = row4[eb + 768]; f3 = ft2[eb + 768]; }

        float cm = MAX4(x0);
        if (v1) cm = fmaxf(cm, MAX4(x1));
        if (v2) cm = fmaxf(cm, MAX4(x2));
        if (v3) cm = fmaxf(cm, MAX4(x3));
        if (cm > m) { Z *= __expf(m - cm); m = cm; }   // rare, ~2/thread

        PROC(x0, f0, eb);
        if (v1) PROC(x1, f1, eb + 256);
        if (v2) PROC(x2, f2, eb + 512);
        if (v3) PROC(x3, f3, eb + 768);
    }
#undef PROC
#undef MAX4

    rm[tid] = m; rz[tid] = Z; rs[tid] = sx;
    __syncthreads();
    for (int s = 128; s > 0; s >>= 1) {
        if (tid < s) {
            float m2 = rm[tid + s], z2 = rz[tid + s];
            float mm = fmaxf(rm[tid], m2);
            rz[tid]  = rz[tid] * __expf(rm[tid] - mm) + z2 * __expf(m2 - mm);
            rm[tid]  = mm;
            rs[tid] += rs[tid + s];
        }
        __syncthreads();
    }
    if (tid == 0) {
        float logZ    = rm[0] + __logf(rz[0]);
        s_logZ        = logZ;
        float logp_t  = s_xt - logZ;
        float sumlogp = rs[0] - (float)VCOLS * logZ;   // sum_j logp[i,j]
        kl_rows[i] = KL_CONST - COEF_T * logp_t - SM_F * sumlogp;
    }
    __syncthreads();
    const float logZ = s_logZ;

    // ---- unlikelihood tail over the candidate list ----
    float acc = 0.0f;
    for (int j = tid; j < i; j += 256) {
        float xv = cand[j];                 // -inf -> p=0 -> term 0
        float p  = __expf(xv - logZ);
        float om = fmaxf(1.0f - p, 1e-5f);
        acc -= __logf(om);
    }
    rs[tid] = acc;
    __syncthreads();
    for (int s = 128; s > 0; s >>= 1) {
        if (tid < s) rs[tid] += rs[tid + s];
        __syncthreads();
    }
    if (tid == 0) custom_rows[i] = rs[0];
}

// ---------------- kernel 5: deterministic final reduction ----------------
__global__ void k_final(const float* __restrict__ kl_rows,
                        const float* __restrict__ custom_rows,
                        const int*   __restrict__ target,
                        float* __restrict__ out) {
    __shared__ float sl[256], sc[256], sn[256];
    int tid = threadIdx.x;
    float L = 0.0f, C = 0.0f, Nn = 0.0f;
    for (int j = tid; j < NROWS; j += 256) {
        L += kl_rows[j];
        C += custom_rows[j];
        int t = target[j];
        if (t != -1 && t != 0) Nn += 1.0f;    // valid & (tgt != PAD)
    }
    sl[tid] = L; sc[tid] = C; sn[tid] = Nn;
    __syncthreads();
    for (int s = 128; s > 0; s >>= 1) {
        if (tid < s) { sl[tid] += sl[tid+s]; sc[tid] += sc[tid+s]; sn[tid] += sn[tid+s]; }
        __syncthreads();
    }
    if (tid == 0) {
        float norm = sn[0];
        out[0] = sl[0] / norm + 0.1f * sc[0] / norm;
    }
}

extern "C" void kernel_launch(void* const* d_in, const int* in_sizes, int n_in,
                              void* d_out, int out_size, void* d_ws, size_t ws_size,
                              hipStream_t stream) {
    const float* X      = (const float*)d_in[0];   // (N, V) float32
    const int*   target = (const int*)d_in[1];     // (N,)   int32
    float*       out    = (float*)d_out;

    char* ws = (char*)d_ws;
    int*            ft32        = (int*)           (ws);                    // 128000 B
    unsigned short* ft16        = (unsigned short*)(ws + 128000);           //  64000 B
    int*            tclean      = (int*)           (ws + 192000);           //  16384 B
    float*          kl_rows     = (float*)         (ws + 192000 + 16384);   //  16384 B
    float*          custom_rows = (float*)         (ws + 192000 + 32768);   //  16384 B

    k_init   <<<(VCOLS + 255) / 256, 256, 0, stream>>>(ft32);
    k_scatter<<<(NROWS + 255) / 256, 256, 0, stream>>>(target, ft32, tclean);
    k_pack   <<<(VCOLS + 255) / 256, 256, 0, stream>>>(ft32, ft16);
    k_main   <<<NROWS,               256, 0, stream>>>(X, target, tclean, ft16,
                                                       kl_rows, custom_rows);
    k_final  <<<1,                   256, 0, stream>>>(kl_rows, custom_rows, target, out);
}